// Round 11
// baseline (365.126 us; speedup 1.0000x reference)
//
#include <hip/hip_runtime.h>
#include <hip/hip_bf16.h>

// Problem constants
#define B_  2
#define N_  2048
#define DM_ 512
#define H_  8
#define DK_ 64
#define DV_ 64
#define BN_ (B_*N_)   // 4096 tokens
#define SPLITS 4

typedef __attribute__((ext_vector_type(8))) short short8;
typedef __attribute__((ext_vector_type(4))) float f32x4;
typedef unsigned short ushort;
typedef __attribute__((address_space(3))) unsigned int lds_u32_t;
typedef const __attribute__((address_space(1))) unsigned int glb_u32_t;

// fp32 -> bf16 round-to-nearest-even
static __device__ __forceinline__ ushort f2bf(float x) {
    unsigned int u = __float_as_uint(x);
    unsigned int r = (u + 0x7FFFu + ((u >> 16) & 1u)) >> 16;
    return (ushort)r;
}
static __device__ __forceinline__ float bf2f(ushort u) {
    return __uint_as_float(((unsigned)u) << 16);
}
// 2^x single instruction
static __device__ __forceinline__ float exp2_fast(float x) {
    float r; asm("v_exp_f32 %0, %1" : "=v"(r) : "v"(x)); return r;
}
// pack two f32 -> 2x bf16 in one dword (lo=a, hi=b)
static __device__ __forceinline__ unsigned cvt_pk_bf16(float a, float b) {
    unsigned r; asm("v_cvt_pk_bf16_f32 %0, %1, %2" : "=v"(r) : "v"(a), "v"(b)); return r;
}

#define LOG2E 1.4426950408889634f

// ---------------------------------------------------------------------------
// prep: ONE kernel for all preprocessing.
//   blocks [0,512)    : Wt[z][n][k] = bf16(W_z[k][n] + WL_z[k][n])  (z=3 no lora)
//   blocks [512,1536) : xbf = bf16(x)
//   blocks [1536,1542): fb[1536] = b + bL
//   block  1542       : zero the 256 split-k counters
// ---------------------------------------------------------------------------
__global__ __launch_bounds__(256) void prep(
        const float* __restrict__ W0, const float* __restrict__ L0,
        const float* __restrict__ W1, const float* __restrict__ L1,
        const float* __restrict__ W2, const float* __restrict__ L2,
        const float* __restrict__ W3, ushort* __restrict__ WtBase,
        const float* __restrict__ x, ushort* __restrict__ xb,
        const float* __restrict__ bq, const float* __restrict__ bqL,
        const float* __restrict__ bk, const float* __restrict__ bkL,
        const float* __restrict__ bv, const float* __restrict__ bvL,
        float* __restrict__ fb, int* __restrict__ cnt) {
    const int bid = blockIdx.x;
    const int t = threadIdx.x;
    if (bid < 512) {
        const int z = bid >> 7, rem = bid & 127;
        const int c0 = (rem & 7) * 64, k0 = (rem >> 3) * 32;
        const float* W  = (z == 0) ? W0 : (z == 1) ? W1 : (z == 2) ? W2 : W3;
        const float* WL = (z == 0) ? L0 : (z == 1) ? L1 : (z == 2) ? L2 : nullptr;
        ushort* Wt = WtBase + (size_t)z * DM_ * DM_;
        __shared__ float Ws[32][65];
        {
            int r = t >> 4, cq = t & 15;
#pragma unroll
            for (int it = 0; it < 2; ++it) {
                int rr = r + it * 16;
                float4 v = *reinterpret_cast<const float4*>(W + (size_t)(k0 + rr) * DM_ + c0 + cq * 4);
                if (WL) {
                    float4 u = *reinterpret_cast<const float4*>(WL + (size_t)(k0 + rr) * DM_ + c0 + cq * 4);
                    v.x += u.x; v.y += u.y; v.z += u.z; v.w += u.w;
                }
                Ws[rr][cq * 4 + 0] = v.x; Ws[rr][cq * 4 + 1] = v.y;
                Ws[rr][cq * 4 + 2] = v.z; Ws[rr][cq * 4 + 3] = v.w;
            }
        }
        __syncthreads();
        {
            int cr = t >> 2, kq = t & 3;
            short8 o;
#pragma unroll
            for (int j = 0; j < 8; ++j) o[j] = (short)f2bf(Ws[kq * 8 + j][cr]);
            *reinterpret_cast<short8*>(Wt + (size_t)(c0 + cr) * DM_ + k0 + kq * 8) = o;
        }
    } else if (bid < 1536) {
        size_t idx = (size_t)(bid - 512) * 256 + t;
        float4 v0 = *reinterpret_cast<const float4*>(x + idx * 8);
        float4 v1 = *reinterpret_cast<const float4*>(x + idx * 8 + 4);
        short8 o;
        o[0] = (short)f2bf(v0.x); o[1] = (short)f2bf(v0.y);
        o[2] = (short)f2bf(v0.z); o[3] = (short)f2bf(v0.w);
        o[4] = (short)f2bf(v1.x); o[5] = (short)f2bf(v1.y);
        o[6] = (short)f2bf(v1.z); o[7] = (short)f2bf(v1.w);
        *reinterpret_cast<short8*>(xb + idx * 8) = o;
    } else if (bid < 1542) {
        int idx = (bid - 1536) * 256 + t;
        if (idx < 3 * DM_) {
            int w = idx >> 9, i = idx & 511;
            const float* a = (w == 0) ? bq : (w == 1) ? bk : bv;
            const float* b = (w == 0) ? bqL : (w == 1) ? bkL : bvL;
            fb[idx] = a[i] + b[i];
        }
    } else {
        cnt[t] = 0;    // 256 split-k counters, re-zeroed every call
    }
}

// ---------------------------------------------------------------------------
// gemm_bf16: C[M][Ncols] = A[M][512] @ Bt[Ncols][512]^T + bias
// 2-phase pipeline: global_load_lds (linear LDS dest, pre-swizzled global src)
// into double buffer; one barrier per K-step.  Tile = 128 x BN.
// MODE 0: qkv epilogue — Q,K bf16 [B,H,N,64] (Q scaled 0.125*log2e);
//         V written TRANSPOSED bf16 [B,H,DV,N] (fused vtrans).
// MODE 1: f32 out [M][512].
// ---------------------------------------------------------------------------
template<int BN, int MODE>
__global__ __launch_bounds__(256) void gemm_bf16(const ushort* __restrict__ A,
                                                 const ushort* __restrict__ Bt,
                                                 const float* __restrict__ bias,
                                                 ushort* __restrict__ Qd,
                                                 ushort* __restrict__ Kd,
                                                 ushort* __restrict__ Vtd,
                                                 float* __restrict__ outF) {
    constexpr int NWC = (BN >= 128) ? 2 : 1;
    constexpr int NWR = 4 / NWC;
    constexpr int MI  = (128 / NWR) / 16;
    constexpr int NJ  = 4;
    constexpr int BIT = BN / 32;          // B staging issues per thread
    const int rt = blockIdx.x, ct = blockIdx.y;
    __shared__ ushort As[2][128 * 64];
    __shared__ ushort Bs[2][BN * 64];
    const int t = threadIdx.x, lane = t & 63, w = t >> 6;
    const int wr = w / NWC, wc = w % NWC;
    const int lg = lane >> 4, lr = lane & 15;
    const int rowbase = wr * (128 / NWR);
    const int colbase = wc * 64;

    f32x4 acc[MI][NJ];
#pragma unroll
    for (int mi = 0; mi < MI; ++mi)
#pragma unroll
        for (int nj = 0; nj < NJ; ++nj) acc[mi][nj] = (f32x4){0.f, 0.f, 0.f, 0.f};

    auto stage = [&](int buf, int k0) {
#pragma unroll
        for (int it = 0; it < 4; ++it) {
            int c = it * 256 + t;
            int r = c >> 3, cq = c & 7;
            int gq = cq ^ (r & 7);
            __builtin_amdgcn_global_load_lds(
                (glb_u32_t*)(A + ((size_t)(rt * 128 + r)) * DM_ + k0 + gq * 8),
                (lds_u32_t*)((char*)(As[buf]) + c * 16), 16, 0, 0);
        }
#pragma unroll
        for (int it = 0; it < BIT; ++it) {
            int c = it * 256 + t;
            int r = c >> 3, cq = c & 7;
            int gq = cq ^ (r & 7);
            __builtin_amdgcn_global_load_lds(
                (glb_u32_t*)(Bt + ((size_t)(ct * BN + r)) * DM_ + k0 + gq * 8),
                (lds_u32_t*)((char*)(Bs[buf]) + c * 16), 16, 0, 0);
        }
    };

    stage(0, 0);
    __syncthreads();

    for (int k0 = 0; k0 < DM_; k0 += 64) {
        const int cur = (k0 >> 6) & 1;
        if (k0 + 64 < DM_) stage(cur ^ 1, k0 + 64);
#pragma unroll
        for (int kh = 0; kh < 2; ++kh) {
            short8 a[MI], b[NJ];
#pragma unroll
            for (int mi = 0; mi < MI; ++mi) {
                int row = rowbase + mi * 16 + lr;
                a[mi] = *reinterpret_cast<const short8*>(
                    (char*)(As[cur]) + row * 128 + (((kh * 4 + lg) ^ (row & 7)) << 4));
            }
#pragma unroll
            for (int nj = 0; nj < NJ; ++nj) {
                int row = colbase + nj * 16 + lr;
                b[nj] = *reinterpret_cast<const short8*>(
                    (char*)(Bs[cur]) + row * 128 + (((kh * 4 + lg) ^ (row & 7)) << 4));
            }
#pragma unroll
            for (int mi = 0; mi < MI; ++mi)
#pragma unroll
                for (int nj = 0; nj < NJ; ++nj)
                    acc[mi][nj] = __builtin_amdgcn_mfma_f32_16x16x32_bf16(
                        a[mi], b[nj], acc[mi][nj], 0, 0, 0);
        }
        __syncthreads();
    }

#pragma unroll
    for (int mi = 0; mi < MI; ++mi) {
#pragma unroll
        for (int nj = 0; nj < NJ; ++nj) {
            int n = ct * BN + colbase + nj * 16 + lr;
            int m0 = rt * 128 + rowbase + mi * 16 + 4 * lg;
            if (MODE == 1) {
#pragma unroll
                for (int r = 0; r < 4; ++r)
                    outF[(size_t)(m0 + r) * DM_ + n] = acc[mi][nj][r] + bias[n];
            } else {
                int ws_ = n >> 9;
                float vv[4];
#pragma unroll
                for (int r = 0; r < 4; ++r) {
                    float v = acc[mi][nj][r] + bias[n];
                    if (ws_ == 0) v *= 0.125f * LOG2E;  // fold softmax scale+log2e into Q
                    vv[r] = v;
                }
                int hd = (n >> 6) & 7, d = n & 63;
                int bb = m0 >> 11, nn = m0 & (N_ - 1);
                if (ws_ < 2) {
                    ushort* op = (ws_ == 0) ? Qd : Kd;
#pragma unroll
                    for (int r = 0; r < 4; ++r)
                        op[(((size_t)(bb * H_ + hd)) * N_ + nn + r) * DK_ + d] = f2bf(vv[r]);
                } else {
                    // V^T: 4 consecutive tokens at one dv -> one 8B store
                    uint2 pk;
                    pk.x = cvt_pk_bf16(vv[0], vv[1]);
                    pk.y = cvt_pk_bf16(vv[2], vv[3]);
                    *reinterpret_cast<uint2*>(
                        Vtd + (((size_t)(bb * H_ + hd)) * DV_ + d) * N_ + nn) = pk;
                }
            }
        }
    }
}

// ---------------------------------------------------------------------------
// attn: flash attention, swapped QK^T, exp2 softmax, KV-split x4 with
// split-k LAST-BLOCK MERGE (device-scope atomics + agent fences).
// grid (N/128, B*H, 4), 512 threads (8 waves x 16 q-rows).
// ---------------------------------------------------------------------------
__global__ __launch_bounds__(512) void attn_mfma(const ushort* __restrict__ Q,
                                                 const ushort* __restrict__ K,
                                                 const ushort* __restrict__ Vt,
                                                 ushort* __restrict__ Opart,
                                                 float2* __restrict__ Ml,
                                                 ushort* __restrict__ Od,
                                                 int* __restrict__ cnt) {
    const int bh = blockIdx.y;
    const int qt = blockIdx.x;
    const int sp = blockIdx.z;
    const int t  = threadIdx.x;
    const int lane = t & 63;
    const int w  = t >> 6;         // 0..7
    const int lg = lane >> 4;
    const int lr = lane & 15;

    __shared__ ushort KsBuf[2][64 * 64];
    __shared__ ushort VtBuf[2][64 * 64];
    __shared__ ushort Ps[8][16 * 64];
    char* PsB = (char*)(Ps[w]);

    const ushort* Kb  = K  + ((size_t)bh * N_ + sp * (N_ / SPLITS)) * DK_;
    const ushort* Vtb = Vt + (size_t)bh * DV_ * N_ + sp * (N_ / SPLITS);

    const int srow = t >> 3, sc = t & 7;

    short8 qf[2];
    {
        const ushort* qrow = Q + ((size_t)bh * N_ + qt * 128 + w * 16 + lr) * DK_;
        qf[0] = *reinterpret_cast<const short8*>(qrow + 8 * lg);
        qf[1] = *reinterpret_cast<const short8*>(qrow + 32 + 8 * lg);
    }

    f32x4 o_[4];
#pragma unroll
    for (int i = 0; i < 4; i++) o_[i] = (f32x4){0.f, 0.f, 0.f, 0.f};
    float m1 = -1e30f, l1 = 0.f;

    uint4 kreg, vreg;
    auto issue = [&](int kt_) {
        kreg = *reinterpret_cast<const uint4*>(Kb  + ((size_t)(kt_ * 64 + srow)) * DK_ + sc * 8);
        vreg = *reinterpret_cast<const uint4*>(Vtb + (size_t)srow * N_ + kt_ * 64 + sc * 8);
    };
    auto wstage = [&](int buf_) {
        *reinterpret_cast<uint4*>((char*)(KsBuf[buf_]) + srow * 128 + ((sc ^ (srow & 7)) << 4)) = kreg;
        *reinterpret_cast<uint4*>((char*)(VtBuf[buf_]) + srow * 128 + ((sc ^ (srow & 7)) << 4)) = vreg;
    };

    issue(0);
    wstage(0);
    __syncthreads();

    const int NT = (N_ / SPLITS) / 64;   // 8 tiles per split
    for (int kt = 0; kt < NT; ++kt) {
        const int cur = kt & 1;
        if (kt + 1 < NT) issue(kt + 1);

        char* KsB = (char*)(KsBuf[cur]);
        char* VtB = (char*)(VtBuf[cur]);

        // ---- S^T = K Q^T : lane holds S[key=kb*16+4lg+r][q=lr], log2 units ----
        f32x4 s[4];
        __builtin_amdgcn_s_setprio(1);
#pragma unroll
        for (int kb = 0; kb < 4; ++kb) {
            int row = kb * 16 + lr;
            short8 k0 = *reinterpret_cast<const short8*>(
                KsB + row * 128 + ((lg ^ (row & 7)) << 4));
            short8 k1 = *reinterpret_cast<const short8*>(
                KsB + row * 128 + (((4 + lg) ^ (row & 7)) << 4));
            f32x4 z = (f32x4){0.f, 0.f, 0.f, 0.f};
            s[kb] = __builtin_amdgcn_mfma_f32_16x16x32_bf16(k0, qf[0], z, 0, 0, 0);
            s[kb] = __builtin_amdgcn_mfma_f32_16x16x32_bf16(k1, qf[1], s[kb], 0, 0, 0);
        }
        __builtin_amdgcn_s_setprio(0);

        // ---- online softmax (base 2), lane-local + 2 xor-shfls ----
        float mx = fmaxf(s[0][0], s[0][1]);
        mx = fmaxf(fmaxf(mx, s[0][2]), s[0][3]);
        mx = fmaxf(fmaxf(mx, s[1][0]), s[1][1]);
        mx = fmaxf(fmaxf(mx, s[1][2]), s[1][3]);
        mx = fmaxf(fmaxf(mx, s[2][0]), s[2][1]);
        mx = fmaxf(fmaxf(mx, s[2][2]), s[2][3]);
        mx = fmaxf(fmaxf(mx, s[3][0]), s[3][1]);
        mx = fmaxf(fmaxf(mx, s[3][2]), s[3][3]);
        mx = fmaxf(mx, __shfl_xor(mx, 16));
        mx = fmaxf(mx, __shfl_xor(mx, 32));

        if (!__all(mx <= m1 + 8.0f)) {      // defer-max (bound p <= 2^8)
            float mnew = fmaxf(m1, mx);
            float alpha = exp2_fast(m1 - mnew);
            m1 = mnew;
            l1 *= alpha;
#pragma unroll
            for (int r = 0; r < 4; ++r) {
                float ar = __shfl(alpha, 4 * lg + r);
#pragma unroll
                for (int db = 0; db < 4; ++db) o_[db][r] *= ar;
            }
        }

        float p[4][4];
        float ps[4];
#pragma unroll
        for (int kb = 0; kb < 4; ++kb) {    // 4 independent partial-sum chains
            p[kb][0] = exp2_fast(s[kb][0] - m1);
            p[kb][1] = exp2_fast(s[kb][1] - m1);
            p[kb][2] = exp2_fast(s[kb][2] - m1);
            p[kb][3] = exp2_fast(s[kb][3] - m1);
            ps[kb] = (p[kb][0] + p[kb][1]) + (p[kb][2] + p[kb][3]);
        }
        float sum = (ps[0] + ps[1]) + (ps[2] + ps[3]);
        sum += __shfl_xor(sum, 16);
        sum += __shfl_xor(sum, 32);
        l1 += sum;

        // ---- P write: one b64 per kb via cvt_pk ----
#pragma unroll
        for (int kb = 0; kb < 4; ++kb) {
            uint2 pk;
            pk.x = cvt_pk_bf16(p[kb][0], p[kb][1]);
            pk.y = cvt_pk_bf16(p[kb][2], p[kb][3]);
            int chunk = 2 * kb + (lg >> 1);
            *reinterpret_cast<uint2*>(
                PsB + lr * 128 + ((chunk ^ (lr & 7)) << 4) + (lg & 1) * 8) = pk;
        }

        // ---- O += P V ----
        short8 pf[2];
        {
            pf[0] = *reinterpret_cast<const short8*>(
                PsB + lr * 128 + ((lg ^ (lr & 7)) << 4));
            pf[1] = *reinterpret_cast<const short8*>(
                PsB + lr * 128 + (((4 + lg) ^ (lr & 7)) << 4));
        }
        __builtin_amdgcn_s_setprio(1);
#pragma unroll
        for (int db = 0; db < 4; ++db) {
            int row = db * 16 + lr;
            short8 v0 = *reinterpret_cast<const short8*>(
                VtB + row * 128 + ((lg ^ (row & 7)) << 4));
            short8 v1 = *reinterpret_cast<const short8*>(
                VtB + row * 128 + (((4 + lg) ^ (row & 7)) << 4));
            o_[db] = __builtin_amdgcn_mfma_f32_16x16x32_bf16(pf[0], v0, o_[db], 0, 0, 0);
            o_[db] = __builtin_amdgcn_mfma_f32_16x16x32_bf16(pf[1], v1, o_[db], 0, 0, 0);
        }
        __builtin_amdgcn_s_setprio(0);

        if (kt + 1 < NT) wstage(cur ^ 1);
        __syncthreads();
    }

    // ---- epilogue: write unnormalized partial O (bf16) + (m,l) ----
    const size_t rowbase = ((size_t)(sp * 16 + bh)) * N_ + qt * 128 + w * 16;
#pragma unroll
    for (int r = 0; r < 4; ++r) {
        int n_loc = 4 * lg + r;
#pragma unroll
        for (int db = 0; db < 4; ++db) {
            Opart[(rowbase + n_loc) * DV_ + db * 16 + lr] = f2bf(o_[db][r]);
        }
    }
    if (lg == 0) {
        Ml[rowbase + lr] = make_float2(m1, l1);
    }

    // ---- split-k finish: last block for (qt,bh) merges the 4 partials ----
    __threadfence();                     // release our partials (agent scope)
    __shared__ int lastflag;
    if (t == 0) lastflag = atomicAdd(&cnt[qt * 16 + bh], 1);
    __syncthreads();
    if (lastflag != SPLITS - 1) return;
    __threadfence();                     // acquire: invalidate stale cache lines

    const int row_loc = t >> 2;          // 0..127
    const int dv0 = (t & 3) * 16;        // 16 dv per thread
    const int n = qt * 128 + row_loc;
    const size_t R = (size_t)16 * N_;
    const size_t mlbase = (size_t)bh * N_ + n;

    float2 ml[SPLITS];
    float M = -1e30f;
#pragma unroll
    for (int s2 = 0; s2 < SPLITS; ++s2) {
        ml[s2] = Ml[(size_t)s2 * R + mlbase];
        M = fmaxf(M, ml[s2].x);
    }
    float wgt[SPLITS], denom = 0.f;
#pragma unroll
    for (int s2 = 0; s2 < SPLITS; ++s2) {
        wgt[s2] = exp2_fast(ml[s2].x - M);
        denom += wgt[s2] * ml[s2].y;
    }
    float inv = 1.f / denom;

    float acc2[16];
#pragma unroll
    for (int j = 0; j < 16; ++j) acc2[j] = 0.f;
#pragma unroll
    for (int s2 = 0; s2 < SPLITS; ++s2) {
        const ushort* src = Opart + ((size_t)s2 * R + mlbase) * DV_ + dv0;
        uint4 u0 = *reinterpret_cast<const uint4*>(src);
        uint4 u1 = *reinterpret_cast<const uint4*>(src + 8);
        const ushort* e0 = reinterpret_cast<const ushort*>(&u0);
        const ushort* e1 = reinterpret_cast<const ushort*>(&u1);
        float wv = wgt[s2];
#pragma unroll
        for (int j = 0; j < 8; ++j) {
            acc2[j]     += wv * bf2f(e0[j]);
            acc2[8 + j] += wv * bf2f(e1[j]);
        }
    }
    uint4 o0, o1;
    unsigned* p0 = reinterpret_cast<unsigned*>(&o0);
    unsigned* p1 = reinterpret_cast<unsigned*>(&o1);
#pragma unroll
    for (int j = 0; j < 4; ++j) {
        p0[j] = cvt_pk_bf16(acc2[2 * j] * inv, acc2[2 * j + 1] * inv);
        p1[j] = cvt_pk_bf16(acc2[8 + 2 * j] * inv, acc2[8 + 2 * j + 1] * inv);
    }
    const int bb = bh >> 3, h = bh & 7;
    ushort* dst = Od + ((size_t)(bb * N_ + n)) * (H_ * DV_) + h * DV_ + dv0;
    *reinterpret_cast<uint4*>(dst) = o0;
    *reinterpret_cast<uint4*>(dst + 8) = o1;
}

// ---------------------------------------------------------------------------
extern "C" void kernel_launch(void* const* d_in, const int* in_sizes, int n_in,
                              void* d_out, int out_size, void* d_ws, size_t ws_size,
                              hipStream_t stream) {
    const float* x   = (const float*)d_in[0];
    const float* Wq  = (const float*)d_in[1];
    const float* bq  = (const float*)d_in[2];
    const float* Wk  = (const float*)d_in[3];
    const float* bk  = (const float*)d_in[4];
    const float* Wv  = (const float*)d_in[5];
    const float* bv  = (const float*)d_in[6];
    const float* WqL = (const float*)d_in[7];
    const float* bqL = (const float*)d_in[8];
    const float* WkL = (const float*)d_in[9];
    const float* bkL = (const float*)d_in[10];
    const float* WvL = (const float*)d_in[11];
    const float* bvL = (const float*)d_in[12];
    const float* Wo  = (const float*)d_in[13];
    const float* bo  = (const float*)d_in[14];

    ushort* Wt_all = (ushort*)d_ws;                          // [2048][512] bf16
    ushort* Wot    = Wt_all + (size_t)3 * DM_ * DM_;
    float*  fb     = (float*)(Wt_all + (size_t)4 * DM_ * DM_); // [1536] f32
    ushort* xbf    = (ushort*)(fb + 3 * DM_);                // [4096][512]
    ushort* Qd     = xbf + (size_t)BN_ * DM_;
    ushort* Kd     = Qd + (size_t)B_ * H_ * N_ * DK_;
    ushort* Vtd    = Kd + (size_t)B_ * H_ * N_ * DK_;        // [B,H,DV,N]
    ushort* Od     = Vtd + (size_t)B_ * H_ * N_ * DV_;       // [B,N,H*DV]
    ushort* Opart  = Od + (size_t)B_ * H_ * N_ * DV_;        // [4][B*H,N,DV]
    float2* Ml     = (float2*)(Opart + (size_t)SPLITS * B_ * H_ * N_ * DV_);
    int*    cnt    = (int*)(Ml + (size_t)SPLITS * B_ * H_ * N_);

    float* out = (float*)d_out;

    prep<<<1543, 256, 0, stream>>>(Wq, WqL, Wk, WkL, Wv, WvL, Wo, Wt_all,
                                   x, xbf, bq, bqL, bk, bkL, bv, bvL, fb, cnt);

    gemm_bf16<64, 0><<<dim3(32, 24), 256, 0, stream>>>(xbf, Wt_all, fb, Qd, Kd, Vtd, nullptr);
    attn_mfma<<<dim3(16, 16, SPLITS), 512, 0, stream>>>(Qd, Kd, Vtd, Opart, Ml, Od, cnt);
    gemm_bf16<64, 1><<<dim3(32, 8), 256, 0, stream>>>(Od, Wot, bo, nullptr, nullptr, nullptr, out);
}

// Round 12
// 64.566 us; speedup vs baseline: 5.6551x; 5.6551x over previous
//
#include <hip/hip_runtime.h>
#include <hip/hip_bf16.h>

// Problem constants
#define B_  2
#define N_  2048
#define DM_ 512
#define H_  8
#define DK_ 64
#define DV_ 64
#define BN_ (B_*N_)   // 4096 tokens
#define SPLITS 4

typedef __attribute__((ext_vector_type(8))) short short8;
typedef __attribute__((ext_vector_type(4))) float f32x4;
typedef unsigned short ushort;
typedef __attribute__((address_space(3))) unsigned int lds_u32_t;
typedef const __attribute__((address_space(1))) unsigned int glb_u32_t;

// fp32 -> bf16 round-to-nearest-even
static __device__ __forceinline__ ushort f2bf(float x) {
    unsigned int u = __float_as_uint(x);
    unsigned int r = (u + 0x7FFFu + ((u >> 16) & 1u)) >> 16;
    return (ushort)r;
}
static __device__ __forceinline__ float bf2f(ushort u) {
    return __uint_as_float(((unsigned)u) << 16);
}
// 2^x single instruction
static __device__ __forceinline__ float exp2_fast(float x) {
    float r; asm("v_exp_f32 %0, %1" : "=v"(r) : "v"(x)); return r;
}
// pack two f32 -> 2x bf16 in one dword (lo=a, hi=b)
static __device__ __forceinline__ unsigned cvt_pk_bf16(float a, float b) {
    unsigned r; asm("v_cvt_pk_bf16_f32 %0, %1, %2" : "=v"(r) : "v"(a), "v"(b)); return r;
}

#define LOG2E 1.4426950408889634f

// ---------------------------------------------------------------------------
// prep: ONE kernel for all preprocessing.
//   blocks [0,512)    : Wt[z][n][k] = bf16(W_z[k][n] + WL_z[k][n])  (z=3 no lora)
//   blocks [512,1536) : xbf = bf16(x)
//   blocks [1536,1542): fb[1536] = b + bL
// ---------------------------------------------------------------------------
__global__ __launch_bounds__(256) void prep(
        const float* __restrict__ W0, const float* __restrict__ L0,
        const float* __restrict__ W1, const float* __restrict__ L1,
        const float* __restrict__ W2, const float* __restrict__ L2,
        const float* __restrict__ W3, ushort* __restrict__ WtBase,
        const float* __restrict__ x, ushort* __restrict__ xb,
        const float* __restrict__ bq, const float* __restrict__ bqL,
        const float* __restrict__ bk, const float* __restrict__ bkL,
        const float* __restrict__ bv, const float* __restrict__ bvL,
        float* __restrict__ fb) {
    const int bid = blockIdx.x;
    const int t = threadIdx.x;
    if (bid < 512) {
        const int z = bid >> 7, rem = bid & 127;
        const int c0 = (rem & 7) * 64, k0 = (rem >> 3) * 32;
        const float* W  = (z == 0) ? W0 : (z == 1) ? W1 : (z == 2) ? W2 : W3;
        const float* WL = (z == 0) ? L0 : (z == 1) ? L1 : (z == 2) ? L2 : nullptr;
        ushort* Wt = WtBase + (size_t)z * DM_ * DM_;
        __shared__ float Ws[32][65];
        {
            int r = t >> 4, cq = t & 15;
#pragma unroll
            for (int it = 0; it < 2; ++it) {
                int rr = r + it * 16;
                float4 v = *reinterpret_cast<const float4*>(W + (size_t)(k0 + rr) * DM_ + c0 + cq * 4);
                if (WL) {
                    float4 u = *reinterpret_cast<const float4*>(WL + (size_t)(k0 + rr) * DM_ + c0 + cq * 4);
                    v.x += u.x; v.y += u.y; v.z += u.z; v.w += u.w;
                }
                Ws[rr][cq * 4 + 0] = v.x; Ws[rr][cq * 4 + 1] = v.y;
                Ws[rr][cq * 4 + 2] = v.z; Ws[rr][cq * 4 + 3] = v.w;
            }
        }
        __syncthreads();
        {
            int cr = t >> 2, kq = t & 3;
            short8 o;
#pragma unroll
            for (int j = 0; j < 8; ++j) o[j] = (short)f2bf(Ws[kq * 8 + j][cr]);
            *reinterpret_cast<short8*>(Wt + (size_t)(c0 + cr) * DM_ + k0 + kq * 8) = o;
        }
    } else if (bid < 1536) {
        size_t idx = (size_t)(bid - 512) * 256 + t;
        float4 v0 = *reinterpret_cast<const float4*>(x + idx * 8);
        float4 v1 = *reinterpret_cast<const float4*>(x + idx * 8 + 4);
        short8 o;
        o[0] = (short)f2bf(v0.x); o[1] = (short)f2bf(v0.y);
        o[2] = (short)f2bf(v0.z); o[3] = (short)f2bf(v0.w);
        o[4] = (short)f2bf(v1.x); o[5] = (short)f2bf(v1.y);
        o[6] = (short)f2bf(v1.z); o[7] = (short)f2bf(v1.w);
        *reinterpret_cast<short8*>(xb + idx * 8) = o;
    } else {
        int idx = (bid - 1536) * 256 + t;
        if (idx < 3 * DM_) {
            int w = idx >> 9, i = idx & 511;
            const float* a = (w == 0) ? bq : (w == 1) ? bk : bv;
            const float* b = (w == 0) ? bqL : (w == 1) ? bkL : bvL;
            fb[idx] = a[i] + b[i];
        }
    }
}

// ---------------------------------------------------------------------------
// gemm_bf16: C[M][Ncols] = A[M][512] @ Bt[Ncols][512]^T + bias
// 2-phase pipeline: global_load_lds (linear LDS dest, pre-swizzled global src)
// into double buffer; one barrier per K-step.  Tile = 128 x BN.
// MODE 0: qkv epilogue — Q,K bf16 [B,H,N,64] (Q scaled 0.125*log2e);
//         V written TRANSPOSED bf16 [B,H,DV,N] (fused vtrans).
// MODE 1: f32 out [M][512].
// ---------------------------------------------------------------------------
template<int BN, int MODE>
__global__ __launch_bounds__(256) void gemm_bf16(const ushort* __restrict__ A,
                                                 const ushort* __restrict__ Bt,
                                                 const float* __restrict__ bias,
                                                 ushort* __restrict__ Qd,
                                                 ushort* __restrict__ Kd,
                                                 ushort* __restrict__ Vtd,
                                                 float* __restrict__ outF) {
    constexpr int NWC = (BN >= 128) ? 2 : 1;
    constexpr int NWR = 4 / NWC;
    constexpr int MI  = (128 / NWR) / 16;
    constexpr int NJ  = 4;
    constexpr int BIT = BN / 32;          // B staging issues per thread
    const int rt = blockIdx.x, ct = blockIdx.y;
    __shared__ ushort As[2][128 * 64];
    __shared__ ushort Bs[2][BN * 64];
    const int t = threadIdx.x, lane = t & 63, w = t >> 6;
    const int wr = w / NWC, wc = w % NWC;
    const int lg = lane >> 4, lr = lane & 15;
    const int rowbase = wr * (128 / NWR);
    const int colbase = wc * 64;

    f32x4 acc[MI][NJ];
#pragma unroll
    for (int mi = 0; mi < MI; ++mi)
#pragma unroll
        for (int nj = 0; nj < NJ; ++nj) acc[mi][nj] = (f32x4){0.f, 0.f, 0.f, 0.f};

    auto stage = [&](int buf, int k0) {
#pragma unroll
        for (int it = 0; it < 4; ++it) {
            int c = it * 256 + t;
            int r = c >> 3, cq = c & 7;
            int gq = cq ^ (r & 7);
            __builtin_amdgcn_global_load_lds(
                (glb_u32_t*)(A + ((size_t)(rt * 128 + r)) * DM_ + k0 + gq * 8),
                (lds_u32_t*)((char*)(As[buf]) + c * 16), 16, 0, 0);
        }
#pragma unroll
        for (int it = 0; it < BIT; ++it) {
            int c = it * 256 + t;
            int r = c >> 3, cq = c & 7;
            int gq = cq ^ (r & 7);
            __builtin_amdgcn_global_load_lds(
                (glb_u32_t*)(Bt + ((size_t)(ct * BN + r)) * DM_ + k0 + gq * 8),
                (lds_u32_t*)((char*)(Bs[buf]) + c * 16), 16, 0, 0);
        }
    };

    stage(0, 0);
    __syncthreads();

    for (int k0 = 0; k0 < DM_; k0 += 64) {
        const int cur = (k0 >> 6) & 1;
        if (k0 + 64 < DM_) stage(cur ^ 1, k0 + 64);
#pragma unroll
        for (int kh = 0; kh < 2; ++kh) {
            short8 a[MI], b[NJ];
#pragma unroll
            for (int mi = 0; mi < MI; ++mi) {
                int row = rowbase + mi * 16 + lr;
                a[mi] = *reinterpret_cast<const short8*>(
                    (char*)(As[cur]) + row * 128 + (((kh * 4 + lg) ^ (row & 7)) << 4));
            }
#pragma unroll
            for (int nj = 0; nj < NJ; ++nj) {
                int row = colbase + nj * 16 + lr;
                b[nj] = *reinterpret_cast<const short8*>(
                    (char*)(Bs[cur]) + row * 128 + (((kh * 4 + lg) ^ (row & 7)) << 4));
            }
#pragma unroll
            for (int mi = 0; mi < MI; ++mi)
#pragma unroll
                for (int nj = 0; nj < NJ; ++nj)
                    acc[mi][nj] = __builtin_amdgcn_mfma_f32_16x16x32_bf16(
                        a[mi], b[nj], acc[mi][nj], 0, 0, 0);
        }
        __syncthreads();
    }

#pragma unroll
    for (int mi = 0; mi < MI; ++mi) {
#pragma unroll
        for (int nj = 0; nj < NJ; ++nj) {
            int n = ct * BN + colbase + nj * 16 + lr;
            int m0 = rt * 128 + rowbase + mi * 16 + 4 * lg;
            if (MODE == 1) {
#pragma unroll
                for (int r = 0; r < 4; ++r)
                    outF[(size_t)(m0 + r) * DM_ + n] = acc[mi][nj][r] + bias[n];
            } else {
                int ws_ = n >> 9;
                float vv[4];
#pragma unroll
                for (int r = 0; r < 4; ++r) {
                    float v = acc[mi][nj][r] + bias[n];
                    if (ws_ == 0) v *= 0.125f * LOG2E;  // fold softmax scale+log2e into Q
                    vv[r] = v;
                }
                int hd = (n >> 6) & 7, d = n & 63;
                int bb = m0 >> 11, nn = m0 & (N_ - 1);
                if (ws_ < 2) {
                    ushort* op = (ws_ == 0) ? Qd : Kd;
#pragma unroll
                    for (int r = 0; r < 4; ++r)
                        op[(((size_t)(bb * H_ + hd)) * N_ + nn + r) * DK_ + d] = f2bf(vv[r]);
                } else {
                    // V^T: 4 consecutive tokens at one dv -> one 8B store
                    uint2 pk;
                    pk.x = cvt_pk_bf16(vv[0], vv[1]);
                    pk.y = cvt_pk_bf16(vv[2], vv[3]);
                    *reinterpret_cast<uint2*>(
                        Vtd + (((size_t)(bb * H_ + hd)) * DV_ + d) * N_ + nn) = pk;
                }
            }
        }
    }
}

// ---------------------------------------------------------------------------
// attn: flash attention, swapped QK^T, exp2 softmax, KV-split x4.
// Reg-staged double-buffered K/V^T (issue-early/write-late), one barrier/tile.
// grid (N/128, B*H, 4), 512 threads (8 waves x 16 q-rows).
// Writes unnormalized partial O (bf16) + (m,l) float2 per row.
// ---------------------------------------------------------------------------
__global__ __launch_bounds__(512) void attn_mfma(const ushort* __restrict__ Q,
                                                 const ushort* __restrict__ K,
                                                 const ushort* __restrict__ Vt,
                                                 ushort* __restrict__ Opart,
                                                 float2* __restrict__ Ml) {
    const int bh = blockIdx.y;
    const int qt = blockIdx.x;
    const int sp = blockIdx.z;
    const int t  = threadIdx.x;
    const int lane = t & 63;
    const int w  = t >> 6;         // 0..7
    const int lg = lane >> 4;
    const int lr = lane & 15;

    __shared__ ushort KsBuf[2][64 * 64];
    __shared__ ushort VtBuf[2][64 * 64];
    __shared__ ushort Ps[8][16 * 64];
    char* PsB = (char*)(Ps[w]);

    const ushort* Kb  = K  + ((size_t)bh * N_ + sp * (N_ / SPLITS)) * DK_;
    const ushort* Vtb = Vt + (size_t)bh * DV_ * N_ + sp * (N_ / SPLITS);

    const int srow = t >> 3, sc = t & 7;

    short8 qf[2];
    {
        const ushort* qrow = Q + ((size_t)bh * N_ + qt * 128 + w * 16 + lr) * DK_;
        qf[0] = *reinterpret_cast<const short8*>(qrow + 8 * lg);
        qf[1] = *reinterpret_cast<const short8*>(qrow + 32 + 8 * lg);
    }

    f32x4 o_[4];
#pragma unroll
    for (int i = 0; i < 4; i++) o_[i] = (f32x4){0.f, 0.f, 0.f, 0.f};
    float m1 = -1e30f, l1 = 0.f;

    uint4 kreg, vreg;
    auto issue = [&](int kt_) {
        kreg = *reinterpret_cast<const uint4*>(Kb  + ((size_t)(kt_ * 64 + srow)) * DK_ + sc * 8);
        vreg = *reinterpret_cast<const uint4*>(Vtb + (size_t)srow * N_ + kt_ * 64 + sc * 8);
    };
    auto wstage = [&](int buf_) {
        *reinterpret_cast<uint4*>((char*)(KsBuf[buf_]) + srow * 128 + ((sc ^ (srow & 7)) << 4)) = kreg;
        *reinterpret_cast<uint4*>((char*)(VtBuf[buf_]) + srow * 128 + ((sc ^ (srow & 7)) << 4)) = vreg;
    };

    issue(0);
    wstage(0);
    __syncthreads();

    const int NT = (N_ / SPLITS) / 64;   // 8 tiles per split
    for (int kt = 0; kt < NT; ++kt) {
        const int cur = kt & 1;
        if (kt + 1 < NT) issue(kt + 1);

        char* KsB = (char*)(KsBuf[cur]);
        char* VtB = (char*)(VtBuf[cur]);

        // ---- S^T = K Q^T : lane holds S[key=kb*16+4lg+r][q=lr], log2 units ----
        f32x4 s[4];
        __builtin_amdgcn_s_setprio(1);
#pragma unroll
        for (int kb = 0; kb < 4; ++kb) {
            int row = kb * 16 + lr;
            short8 k0 = *reinterpret_cast<const short8*>(
                KsB + row * 128 + ((lg ^ (row & 7)) << 4));
            short8 k1 = *reinterpret_cast<const short8*>(
                KsB + row * 128 + (((4 + lg) ^ (row & 7)) << 4));
            f32x4 z = (f32x4){0.f, 0.f, 0.f, 0.f};
            s[kb] = __builtin_amdgcn_mfma_f32_16x16x32_bf16(k0, qf[0], z, 0, 0, 0);
            s[kb] = __builtin_amdgcn_mfma_f32_16x16x32_bf16(k1, qf[1], s[kb], 0, 0, 0);
        }
        __builtin_amdgcn_s_setprio(0);

        // ---- online softmax (base 2), lane-local + 2 xor-shfls ----
        // max3-friendly tree: fmaxf(fmaxf(a,b),c) fuses to v_max3_f32
        float mx = fmaxf(s[0][0], s[0][1]);
        mx = fmaxf(fmaxf(mx, s[0][2]), s[0][3]);
        mx = fmaxf(fmaxf(mx, s[1][0]), s[1][1]);
        mx = fmaxf(fmaxf(mx, s[1][2]), s[1][3]);
        mx = fmaxf(fmaxf(mx, s[2][0]), s[2][1]);
        mx = fmaxf(fmaxf(mx, s[2][2]), s[2][3]);
        mx = fmaxf(fmaxf(mx, s[3][0]), s[3][1]);
        mx = fmaxf(fmaxf(mx, s[3][2]), s[3][3]);
        mx = fmaxf(mx, __shfl_xor(mx, 16));
        mx = fmaxf(mx, __shfl_xor(mx, 32));

        if (!__all(mx <= m1 + 8.0f)) {      // defer-max (bound p <= 2^8)
            float mnew = fmaxf(m1, mx);
            float alpha = exp2_fast(m1 - mnew);
            m1 = mnew;
            l1 *= alpha;
#pragma unroll
            for (int r = 0; r < 4; ++r) {
                float ar = __shfl(alpha, 4 * lg + r);
#pragma unroll
                for (int db = 0; db < 4; ++db) o_[db][r] *= ar;
            }
        }

        float p[4][4];
        float ps[4];
#pragma unroll
        for (int kb = 0; kb < 4; ++kb) {    // 4 independent partial-sum chains
            p[kb][0] = exp2_fast(s[kb][0] - m1);
            p[kb][1] = exp2_fast(s[kb][1] - m1);
            p[kb][2] = exp2_fast(s[kb][2] - m1);
            p[kb][3] = exp2_fast(s[kb][3] - m1);
            ps[kb] = (p[kb][0] + p[kb][1]) + (p[kb][2] + p[kb][3]);
        }
        float sum = (ps[0] + ps[1]) + (ps[2] + ps[3]);
        sum += __shfl_xor(sum, 16);
        sum += __shfl_xor(sum, 32);
        l1 += sum;

        // ---- P write: one b64 per kb via cvt_pk ----
#pragma unroll
        for (int kb = 0; kb < 4; ++kb) {
            uint2 pk;
            pk.x = cvt_pk_bf16(p[kb][0], p[kb][1]);
            pk.y = cvt_pk_bf16(p[kb][2], p[kb][3]);
            int chunk = 2 * kb + (lg >> 1);
            *reinterpret_cast<uint2*>(
                PsB + lr * 128 + ((chunk ^ (lr & 7)) << 4) + (lg & 1) * 8) = pk;
        }

        // ---- O += P V ----
        short8 pf[2];
        {
            pf[0] = *reinterpret_cast<const short8*>(
                PsB + lr * 128 + ((lg ^ (lr & 7)) << 4));
            pf[1] = *reinterpret_cast<const short8*>(
                PsB + lr * 128 + (((4 + lg) ^ (lr & 7)) << 4));
        }
        __builtin_amdgcn_s_setprio(1);
#pragma unroll
        for (int db = 0; db < 4; ++db) {
            int row = db * 16 + lr;
            short8 v0 = *reinterpret_cast<const short8*>(
                VtB + row * 128 + ((lg ^ (row & 7)) << 4));
            short8 v1 = *reinterpret_cast<const short8*>(
                VtB + row * 128 + (((4 + lg) ^ (row & 7)) << 4));
            o_[db] = __builtin_amdgcn_mfma_f32_16x16x32_bf16(pf[0], v0, o_[db], 0, 0, 0);
            o_[db] = __builtin_amdgcn_mfma_f32_16x16x32_bf16(pf[1], v1, o_[db], 0, 0, 0);
        }
        __builtin_amdgcn_s_setprio(0);

        if (kt + 1 < NT) wstage(cur ^ 1);
        __syncthreads();
    }

    // ---- epilogue: write unnormalized partial O (bf16) + (m,l) ----
    const size_t rowbase = ((size_t)(sp * 16 + bh)) * N_ + qt * 128 + w * 16;
#pragma unroll
    for (int r = 0; r < 4; ++r) {
        int n_loc = 4 * lg + r;
#pragma unroll
        for (int db = 0; db < 4; ++db) {
            Opart[(rowbase + n_loc) * DV_ + db * 16 + lr] = f2bf(o_[db][r]);
        }
    }
    if (lg == 0) {
        Ml[rowbase + lr] = make_float2(m1, l1);
    }
}

// ---------------------------------------------------------------------------
// merge: combine 4 kv-split partials -> final attn output bf16 [B,N,H*DV]
// ---------------------------------------------------------------------------
__global__ __launch_bounds__(256) void merge_splits(const ushort* __restrict__ Opart,
                                                    const float2* __restrict__ Ml,
                                                    ushort* __restrict__ Od) {
    int gid = blockIdx.x * 256 + threadIdx.x;
    int row = gid >> 4;               // [0, 32768) = bh*2048 + n
    int dv  = (gid & 15) * 4;
    const int R = 16 * N_;            // rows per split
    float2 ml[SPLITS];
    float M = -1e30f;
#pragma unroll
    for (int s = 0; s < SPLITS; ++s) { ml[s] = Ml[(size_t)s * R + row]; M = fmaxf(M, ml[s].x); }
    float wgt[SPLITS], denom = 0.f;
#pragma unroll
    for (int s = 0; s < SPLITS; ++s) { wgt[s] = exp2_fast(ml[s].x - M); denom += wgt[s] * ml[s].y; }
    float inv = 1.f / denom;
    float a0 = 0.f, a1 = 0.f, a2 = 0.f, a3 = 0.f;
#pragma unroll
    for (int s = 0; s < SPLITS; ++s) {
        uint2 u = *reinterpret_cast<const uint2*>(Opart + ((size_t)s * R + row) * DV_ + dv);
        const ushort* e = reinterpret_cast<const ushort*>(&u);
        a0 += wgt[s] * bf2f(e[0]); a1 += wgt[s] * bf2f(e[1]);
        a2 += wgt[s] * bf2f(e[2]); a3 += wgt[s] * bf2f(e[3]);
    }
    uint2 o;
    o.x = cvt_pk_bf16(a0 * inv, a1 * inv);
    o.y = cvt_pk_bf16(a2 * inv, a3 * inv);
    int bh = row >> 11, n = row & (N_ - 1);
    int bb = bh >> 3, h = bh & 7;
    *reinterpret_cast<uint2*>(Od + ((size_t)(bb * N_ + n)) * (H_ * DV_) + h * DV_ + dv) = o;
}

// ---------------------------------------------------------------------------
extern "C" void kernel_launch(void* const* d_in, const int* in_sizes, int n_in,
                              void* d_out, int out_size, void* d_ws, size_t ws_size,
                              hipStream_t stream) {
    const float* x   = (const float*)d_in[0];
    const float* Wq  = (const float*)d_in[1];
    const float* bq  = (const float*)d_in[2];
    const float* Wk  = (const float*)d_in[3];
    const float* bk  = (const float*)d_in[4];
    const float* Wv  = (const float*)d_in[5];
    const float* bv  = (const float*)d_in[6];
    const float* WqL = (const float*)d_in[7];
    const float* bqL = (const float*)d_in[8];
    const float* WkL = (const float*)d_in[9];
    const float* bkL = (const float*)d_in[10];
    const float* WvL = (const float*)d_in[11];
    const float* bvL = (const float*)d_in[12];
    const float* Wo  = (const float*)d_in[13];
    const float* bo  = (const float*)d_in[14];

    ushort* Wt_all = (ushort*)d_ws;                          // [2048][512] bf16
    ushort* Wot    = Wt_all + (size_t)3 * DM_ * DM_;
    float*  fb     = (float*)(Wt_all + (size_t)4 * DM_ * DM_); // [1536] f32
    ushort* xbf    = (ushort*)(fb + 3 * DM_);                // [4096][512]
    ushort* Qd     = xbf + (size_t)BN_ * DM_;
    ushort* Kd     = Qd + (size_t)B_ * H_ * N_ * DK_;
    ushort* Vtd    = Kd + (size_t)B_ * H_ * N_ * DK_;        // [B,H,DV,N]
    ushort* Od     = Vtd + (size_t)B_ * H_ * N_ * DV_;       // [B,N,H*DV]
    ushort* Opart  = Od + (size_t)B_ * H_ * N_ * DV_;        // [4][B*H,N,DV]
    float2* Ml     = (float2*)(Opart + (size_t)SPLITS * B_ * H_ * N_ * DV_);

    float* out = (float*)d_out;

    prep<<<1542, 256, 0, stream>>>(Wq, WqL, Wk, WkL, Wv, WvL, Wo, Wt_all,
                                   x, xbf, bq, bqL, bk, bkL, bv, bvL, fb);

    gemm_bf16<64, 0><<<dim3(32, 24), 256, 0, stream>>>(xbf, Wt_all, fb, Qd, Kd, Vtd, nullptr);
    attn_mfma<<<dim3(16, 16, SPLITS), 512, 0, stream>>>(Qd, Kd, Vtd, Opart, Ml);
    merge_splits<<<(B_ * H_ * N_ * 16) / 256, 256, 0, stream>>>(Opart, Ml, Od);
    gemm_bf16<64, 1><<<dim3(32, 8), 256, 0, stream>>>(Od, Wot, bo, nullptr, nullptr, nullptr, out);
}

// Round 13
// 63.732 us; speedup vs baseline: 5.7291x; 1.0131x over previous
//
#include <hip/hip_runtime.h>
#include <hip/hip_bf16.h>

// Problem constants
#define B_  2
#define N_  2048
#define DM_ 512
#define H_  8
#define DK_ 64
#define DV_ 64
#define BN_ (B_*N_)   // 4096 tokens
#define SPLITS 4

typedef __attribute__((ext_vector_type(8))) short short8;
typedef __attribute__((ext_vector_type(4))) float f32x4;
typedef unsigned short ushort;
typedef __attribute__((address_space(3))) unsigned int lds_u32_t;
typedef const __attribute__((address_space(1))) unsigned int glb_u32_t;

// fp32 -> bf16 round-to-nearest-even
static __device__ __forceinline__ ushort f2bf(float x) {
    unsigned int u = __float_as_uint(x);
    unsigned int r = (u + 0x7FFFu + ((u >> 16) & 1u)) >> 16;
    return (ushort)r;
}
static __device__ __forceinline__ float bf2f(ushort u) {
    return __uint_as_float(((unsigned)u) << 16);
}
// 2^x single instruction
static __device__ __forceinline__ float exp2_fast(float x) {
    float r; asm("v_exp_f32 %0, %1" : "=v"(r) : "v"(x)); return r;
}
// pack two f32 -> 2x bf16 in one dword (lo=a, hi=b)
static __device__ __forceinline__ unsigned cvt_pk_bf16(float a, float b) {
    unsigned r; asm("v_cvt_pk_bf16_f32 %0, %1, %2" : "=v"(r) : "v"(a), "v"(b)); return r;
}

#define LOG2E 1.4426950408889634f

// ---------------------------------------------------------------------------
// prep: ONE kernel for all preprocessing.
//   blocks [0,512)    : Wt[z][n][k] = bf16(W_z[k][n] + WL_z[k][n])  (z=3 no lora)
//   blocks [512,1536) : xbf = bf16(x)
//   blocks [1536,1542): fb[1536] = b + bL
// ---------------------------------------------------------------------------
__global__ __launch_bounds__(256) void prep(
        const float* __restrict__ W0, const float* __restrict__ L0,
        const float* __restrict__ W1, const float* __restrict__ L1,
        const float* __restrict__ W2, const float* __restrict__ L2,
        const float* __restrict__ W3, ushort* __restrict__ WtBase,
        const float* __restrict__ x, ushort* __restrict__ xb,
        const float* __restrict__ bq, const float* __restrict__ bqL,
        const float* __restrict__ bk, const float* __restrict__ bkL,
        const float* __restrict__ bv, const float* __restrict__ bvL,
        float* __restrict__ fb) {
    const int bid = blockIdx.x;
    const int t = threadIdx.x;
    if (bid < 512) {
        const int z = bid >> 7, rem = bid & 127;
        const int c0 = (rem & 7) * 64, k0 = (rem >> 3) * 32;
        const float* W  = (z == 0) ? W0 : (z == 1) ? W1 : (z == 2) ? W2 : W3;
        const float* WL = (z == 0) ? L0 : (z == 1) ? L1 : (z == 2) ? L2 : nullptr;
        ushort* Wt = WtBase + (size_t)z * DM_ * DM_;
        __shared__ float Ws[32][65];
        {
            int r = t >> 4, cq = t & 15;
#pragma unroll
            for (int it = 0; it < 2; ++it) {
                int rr = r + it * 16;
                float4 v = *reinterpret_cast<const float4*>(W + (size_t)(k0 + rr) * DM_ + c0 + cq * 4);
                if (WL) {
                    float4 u = *reinterpret_cast<const float4*>(WL + (size_t)(k0 + rr) * DM_ + c0 + cq * 4);
                    v.x += u.x; v.y += u.y; v.z += u.z; v.w += u.w;
                }
                Ws[rr][cq * 4 + 0] = v.x; Ws[rr][cq * 4 + 1] = v.y;
                Ws[rr][cq * 4 + 2] = v.z; Ws[rr][cq * 4 + 3] = v.w;
            }
        }
        __syncthreads();
        {
            int cr = t >> 2, kq = t & 3;
            short8 o;
#pragma unroll
            for (int j = 0; j < 8; ++j) o[j] = (short)f2bf(Ws[kq * 8 + j][cr]);
            *reinterpret_cast<short8*>(Wt + (size_t)(c0 + cr) * DM_ + k0 + kq * 8) = o;
        }
    } else if (bid < 1536) {
        size_t idx = (size_t)(bid - 512) * 256 + t;
        float4 v0 = *reinterpret_cast<const float4*>(x + idx * 8);
        float4 v1 = *reinterpret_cast<const float4*>(x + idx * 8 + 4);
        short8 o;
        o[0] = (short)f2bf(v0.x); o[1] = (short)f2bf(v0.y);
        o[2] = (short)f2bf(v0.z); o[3] = (short)f2bf(v0.w);
        o[4] = (short)f2bf(v1.x); o[5] = (short)f2bf(v1.y);
        o[6] = (short)f2bf(v1.z); o[7] = (short)f2bf(v1.w);
        *reinterpret_cast<short8*>(xb + idx * 8) = o;
    } else {
        int idx = (bid - 1536) * 256 + t;
        if (idx < 3 * DM_) {
            int w = idx >> 9, i = idx & 511;
            const float* a = (w == 0) ? bq : (w == 1) ? bk : bv;
            const float* b = (w == 0) ? bqL : (w == 1) ? bkL : bvL;
            fb[idx] = a[i] + b[i];
        }
    }
}

// ---------------------------------------------------------------------------
// gemm_bf16: C[M][Ncols] = A[M][512] @ Bt[Ncols][512]^T + bias
// 2-phase pipeline: global_load_lds (linear LDS dest, pre-swizzled global src)
// into double buffer; one barrier per K-step.  Tile = 128 x BN.
// MODE 0: qkv epilogue — Q,K bf16 [B,H,N,64] (Q scaled 0.125*log2e);
//         V written TRANSPOSED bf16 [B,H,DV,N] (fused vtrans).
// MODE 1: f32 out [M][512].
// ---------------------------------------------------------------------------
template<int BN, int MODE>
__global__ __launch_bounds__(256) void gemm_bf16(const ushort* __restrict__ A,
                                                 const ushort* __restrict__ Bt,
                                                 const float* __restrict__ bias,
                                                 ushort* __restrict__ Qd,
                                                 ushort* __restrict__ Kd,
                                                 ushort* __restrict__ Vtd,
                                                 float* __restrict__ outF) {
    constexpr int NWC = (BN >= 128) ? 2 : 1;
    constexpr int NWR = 4 / NWC;
    constexpr int MI  = (128 / NWR) / 16;
    constexpr int NJ  = BN / (NWC * 16);  // n-frags per wave (covers exactly BN)
    constexpr int BIT = BN / 32;          // B staging issues per thread
    const int rt = blockIdx.x, ct = blockIdx.y;
    __shared__ ushort As[2][128 * 64];
    __shared__ ushort Bs[2][BN * 64];
    const int t = threadIdx.x, lane = t & 63, w = t >> 6;
    const int wr = w / NWC, wc = w % NWC;
    const int lg = lane >> 4, lr = lane & 15;
    const int rowbase = wr * (128 / NWR);
    const int colbase = wc * (BN / NWC);

    f32x4 acc[MI][NJ];
#pragma unroll
    for (int mi = 0; mi < MI; ++mi)
#pragma unroll
        for (int nj = 0; nj < NJ; ++nj) acc[mi][nj] = (f32x4){0.f, 0.f, 0.f, 0.f};

    auto stage = [&](int buf, int k0) {
#pragma unroll
        for (int it = 0; it < 4; ++it) {
            int c = it * 256 + t;
            int r = c >> 3, cq = c & 7;
            int gq = cq ^ (r & 7);
            __builtin_amdgcn_global_load_lds(
                (glb_u32_t*)(A + ((size_t)(rt * 128 + r)) * DM_ + k0 + gq * 8),
                (lds_u32_t*)((char*)(As[buf]) + c * 16), 16, 0, 0);
        }
#pragma unroll
        for (int it = 0; it < BIT; ++it) {
            int c = it * 256 + t;
            int r = c >> 3, cq = c & 7;
            int gq = cq ^ (r & 7);
            __builtin_amdgcn_global_load_lds(
                (glb_u32_t*)(Bt + ((size_t)(ct * BN + r)) * DM_ + k0 + gq * 8),
                (lds_u32_t*)((char*)(Bs[buf]) + c * 16), 16, 0, 0);
        }
    };

    stage(0, 0);
    __syncthreads();

    for (int k0 = 0; k0 < DM_; k0 += 64) {
        const int cur = (k0 >> 6) & 1;
        if (k0 + 64 < DM_) stage(cur ^ 1, k0 + 64);
#pragma unroll
        for (int kh = 0; kh < 2; ++kh) {
            short8 a[MI], b[NJ];
#pragma unroll
            for (int mi = 0; mi < MI; ++mi) {
                int row = rowbase + mi * 16 + lr;
                a[mi] = *reinterpret_cast<const short8*>(
                    (char*)(As[cur]) + row * 128 + (((kh * 4 + lg) ^ (row & 7)) << 4));
            }
#pragma unroll
            for (int nj = 0; nj < NJ; ++nj) {
                int row = colbase + nj * 16 + lr;
                b[nj] = *reinterpret_cast<const short8*>(
                    (char*)(Bs[cur]) + row * 128 + (((kh * 4 + lg) ^ (row & 7)) << 4));
            }
#pragma unroll
            for (int mi = 0; mi < MI; ++mi)
#pragma unroll
                for (int nj = 0; nj < NJ; ++nj)
                    acc[mi][nj] = __builtin_amdgcn_mfma_f32_16x16x32_bf16(
                        a[mi], b[nj], acc[mi][nj], 0, 0, 0);
        }
        __syncthreads();
    }

#pragma unroll
    for (int mi = 0; mi < MI; ++mi) {
#pragma unroll
        for (int nj = 0; nj < NJ; ++nj) {
            int n = ct * BN + colbase + nj * 16 + lr;
            int m0 = rt * 128 + rowbase + mi * 16 + 4 * lg;
            if (MODE == 1) {
#pragma unroll
                for (int r = 0; r < 4; ++r)
                    outF[(size_t)(m0 + r) * DM_ + n] = acc[mi][nj][r] + bias[n];
            } else {
                int ws_ = n >> 9;
                float vv[4];
#pragma unroll
                for (int r = 0; r < 4; ++r) {
                    float v = acc[mi][nj][r] + bias[n];
                    if (ws_ == 0) v *= 0.125f * LOG2E;  // fold softmax scale+log2e into Q
                    vv[r] = v;
                }
                int hd = (n >> 6) & 7, d = n & 63;
                int bb = m0 >> 11, nn = m0 & (N_ - 1);
                if (ws_ < 2) {
                    ushort* op = (ws_ == 0) ? Qd : Kd;
#pragma unroll
                    for (int r = 0; r < 4; ++r)
                        op[(((size_t)(bb * H_ + hd)) * N_ + nn + r) * DK_ + d] = f2bf(vv[r]);
                } else {
                    // V^T: 4 consecutive tokens at one dv -> one 8B store
                    uint2 pk;
                    pk.x = cvt_pk_bf16(vv[0], vv[1]);
                    pk.y = cvt_pk_bf16(vv[2], vv[3]);
                    *reinterpret_cast<uint2*>(
                        Vtd + (((size_t)(bb * H_ + hd)) * DV_ + d) * N_ + nn) = pk;
                }
            }
        }
    }
}

// ---------------------------------------------------------------------------
// attn: flash attention, swapped QK^T, exp2 softmax, KV-split x4.
// Reg-staged double-buffered K/V^T (issue-early/write-late), one barrier/tile.
// grid (N/128, B*H, 4), 512 threads (8 waves x 16 q-rows).
// Writes unnormalized partial O (bf16) + (m,l) float2 per row.
// ---------------------------------------------------------------------------
__global__ __launch_bounds__(512) void attn_mfma(const ushort* __restrict__ Q,
                                                 const ushort* __restrict__ K,
                                                 const ushort* __restrict__ Vt,
                                                 ushort* __restrict__ Opart,
                                                 float2* __restrict__ Ml) {
    const int bh = blockIdx.y;
    const int qt = blockIdx.x;
    const int sp = blockIdx.z;
    const int t  = threadIdx.x;
    const int lane = t & 63;
    const int w  = t >> 6;         // 0..7
    const int lg = lane >> 4;
    const int lr = lane & 15;

    __shared__ ushort KsBuf[2][64 * 64];
    __shared__ ushort VtBuf[2][64 * 64];
    __shared__ ushort Ps[8][16 * 64];
    char* PsB = (char*)(Ps[w]);

    const ushort* Kb  = K  + ((size_t)bh * N_ + sp * (N_ / SPLITS)) * DK_;
    const ushort* Vtb = Vt + (size_t)bh * DV_ * N_ + sp * (N_ / SPLITS);

    const int srow = t >> 3, sc = t & 7;

    short8 qf[2];
    {
        const ushort* qrow = Q + ((size_t)bh * N_ + qt * 128 + w * 16 + lr) * DK_;
        qf[0] = *reinterpret_cast<const short8*>(qrow + 8 * lg);
        qf[1] = *reinterpret_cast<const short8*>(qrow + 32 + 8 * lg);
    }

    f32x4 o_[4];
#pragma unroll
    for (int i = 0; i < 4; i++) o_[i] = (f32x4){0.f, 0.f, 0.f, 0.f};
    float m1 = -1e30f, l1 = 0.f;

    uint4 kreg, vreg;
    auto issue = [&](int kt_) {
        kreg = *reinterpret_cast<const uint4*>(Kb  + ((size_t)(kt_ * 64 + srow)) * DK_ + sc * 8);
        vreg = *reinterpret_cast<const uint4*>(Vtb + (size_t)srow * N_ + kt_ * 64 + sc * 8);
    };
    auto wstage = [&](int buf_) {
        *reinterpret_cast<uint4*>((char*)(KsBuf[buf_]) + srow * 128 + ((sc ^ (srow & 7)) << 4)) = kreg;
        *reinterpret_cast<uint4*>((char*)(VtBuf[buf_]) + srow * 128 + ((sc ^ (srow & 7)) << 4)) = vreg;
    };

    issue(0);
    wstage(0);
    __syncthreads();

    const int NT = (N_ / SPLITS) / 64;   // 8 tiles per split
    for (int kt = 0; kt < NT; ++kt) {
        const int cur = kt & 1;
        if (kt + 1 < NT) issue(kt + 1);

        char* KsB = (char*)(KsBuf[cur]);
        char* VtB = (char*)(VtBuf[cur]);

        // ---- S^T = K Q^T : lane holds S[key=kb*16+4lg+r][q=lr], log2 units ----
        f32x4 s[4];
        __builtin_amdgcn_s_setprio(1);
#pragma unroll
        for (int kb = 0; kb < 4; ++kb) {
            int row = kb * 16 + lr;
            short8 k0 = *reinterpret_cast<const short8*>(
                KsB + row * 128 + ((lg ^ (row & 7)) << 4));
            short8 k1 = *reinterpret_cast<const short8*>(
                KsB + row * 128 + (((4 + lg) ^ (row & 7)) << 4));
            f32x4 z = (f32x4){0.f, 0.f, 0.f, 0.f};
            s[kb] = __builtin_amdgcn_mfma_f32_16x16x32_bf16(k0, qf[0], z, 0, 0, 0);
            s[kb] = __builtin_amdgcn_mfma_f32_16x16x32_bf16(k1, qf[1], s[kb], 0, 0, 0);
        }
        __builtin_amdgcn_s_setprio(0);

        // ---- online softmax (base 2), lane-local + 2 xor-shfls ----
        // max3-friendly tree: fmaxf(fmaxf(a,b),c) fuses to v_max3_f32
        float mx = fmaxf(s[0][0], s[0][1]);
        mx = fmaxf(fmaxf(mx, s[0][2]), s[0][3]);
        mx = fmaxf(fmaxf(mx, s[1][0]), s[1][1]);
        mx = fmaxf(fmaxf(mx, s[1][2]), s[1][3]);
        mx = fmaxf(fmaxf(mx, s[2][0]), s[2][1]);
        mx = fmaxf(fmaxf(mx, s[2][2]), s[2][3]);
        mx = fmaxf(fmaxf(mx, s[3][0]), s[3][1]);
        mx = fmaxf(fmaxf(mx, s[3][2]), s[3][3]);
        mx = fmaxf(mx, __shfl_xor(mx, 16));
        mx = fmaxf(mx, __shfl_xor(mx, 32));

        if (!__all(mx <= m1 + 8.0f)) {      // defer-max (bound p <= 2^8)
            float mnew = fmaxf(m1, mx);
            float alpha = exp2_fast(m1 - mnew);
            m1 = mnew;
            l1 *= alpha;
#pragma unroll
            for (int r = 0; r < 4; ++r) {
                float ar = __shfl(alpha, 4 * lg + r);
#pragma unroll
                for (int db = 0; db < 4; ++db) o_[db][r] *= ar;
            }
        }

        float p[4][4];
        float ps[4];
#pragma unroll
        for (int kb = 0; kb < 4; ++kb) {    // 4 independent partial-sum chains
            p[kb][0] = exp2_fast(s[kb][0] - m1);
            p[kb][1] = exp2_fast(s[kb][1] - m1);
            p[kb][2] = exp2_fast(s[kb][2] - m1);
            p[kb][3] = exp2_fast(s[kb][3] - m1);
            ps[kb] = (p[kb][0] + p[kb][1]) + (p[kb][2] + p[kb][3]);
        }
        float sum = (ps[0] + ps[1]) + (ps[2] + ps[3]);
        sum += __shfl_xor(sum, 16);
        sum += __shfl_xor(sum, 32);
        l1 += sum;

        // ---- P write: one b64 per kb via cvt_pk ----
#pragma unroll
        for (int kb = 0; kb < 4; ++kb) {
            uint2 pk;
            pk.x = cvt_pk_bf16(p[kb][0], p[kb][1]);
            pk.y = cvt_pk_bf16(p[kb][2], p[kb][3]);
            int chunk = 2 * kb + (lg >> 1);
            *reinterpret_cast<uint2*>(
                PsB + lr * 128 + ((chunk ^ (lr & 7)) << 4) + (lg & 1) * 8) = pk;
        }

        // ---- O += P V ----
        short8 pf[2];
        {
            pf[0] = *reinterpret_cast<const short8*>(
                PsB + lr * 128 + ((lg ^ (lr & 7)) << 4));
            pf[1] = *reinterpret_cast<const short8*>(
                PsB + lr * 128 + (((4 + lg) ^ (lr & 7)) << 4));
        }
        __builtin_amdgcn_s_setprio(1);
#pragma unroll
        for (int db = 0; db < 4; ++db) {
            int row = db * 16 + lr;
            short8 v0 = *reinterpret_cast<const short8*>(
                VtB + row * 128 + ((lg ^ (row & 7)) << 4));
            short8 v1 = *reinterpret_cast<const short8*>(
                VtB + row * 128 + (((4 + lg) ^ (row & 7)) << 4));
            o_[db] = __builtin_amdgcn_mfma_f32_16x16x32_bf16(pf[0], v0, o_[db], 0, 0, 0);
            o_[db] = __builtin_amdgcn_mfma_f32_16x16x32_bf16(pf[1], v1, o_[db], 0, 0, 0);
        }
        __builtin_amdgcn_s_setprio(0);

        if (kt + 1 < NT) wstage(cur ^ 1);
        __syncthreads();
    }

    // ---- epilogue: write unnormalized partial O (bf16) + (m,l) ----
    const size_t rowbase = ((size_t)(sp * 16 + bh)) * N_ + qt * 128 + w * 16;
#pragma unroll
    for (int r = 0; r < 4; ++r) {
        int n_loc = 4 * lg + r;
#pragma unroll
        for (int db = 0; db < 4; ++db) {
            Opart[(rowbase + n_loc) * DV_ + db * 16 + lr] = f2bf(o_[db][r]);
        }
    }
    if (lg == 0) {
        Ml[rowbase + lr] = make_float2(m1, l1);
    }
}

// ---------------------------------------------------------------------------
// merge: combine 4 kv-split partials -> final attn output bf16 [B,N,H*DV]
// ---------------------------------------------------------------------------
__global__ __launch_bounds__(256) void merge_splits(const ushort* __restrict__ Opart,
                                                    const float2* __restrict__ Ml,
                                                    ushort* __restrict__ Od) {
    int gid = blockIdx.x * 256 + threadIdx.x;
    int row = gid >> 4;               // [0, 32768) = bh*2048 + n
    int dv  = (gid & 15) * 4;
    const int R = 16 * N_;            // rows per split
    float2 ml[SPLITS];
    float M = -1e30f;
#pragma unroll
    for (int s = 0; s < SPLITS; ++s) { ml[s] = Ml[(size_t)s * R + row]; M = fmaxf(M, ml[s].x); }
    float wgt[SPLITS], denom = 0.f;
#pragma unroll
    for (int s = 0; s < SPLITS; ++s) { wgt[s] = exp2_fast(ml[s].x - M); denom += wgt[s] * ml[s].y; }
    float inv = 1.f / denom;
    float a0 = 0.f, a1 = 0.f, a2 = 0.f, a3 = 0.f;
#pragma unroll
    for (int s = 0; s < SPLITS; ++s) {
        uint2 u = *reinterpret_cast<const uint2*>(Opart + ((size_t)s * R + row) * DV_ + dv);
        const ushort* e = reinterpret_cast<const ushort*>(&u);
        a0 += wgt[s] * bf2f(e[0]); a1 += wgt[s] * bf2f(e[1]);
        a2 += wgt[s] * bf2f(e[2]); a3 += wgt[s] * bf2f(e[3]);
    }
    uint2 o;
    o.x = cvt_pk_bf16(a0 * inv, a1 * inv);
    o.y = cvt_pk_bf16(a2 * inv, a3 * inv);
    int bh = row >> 11, n = row & (N_ - 1);
    int bb = bh >> 3, h = bh & 7;
    *reinterpret_cast<uint2*>(Od + ((size_t)(bb * N_ + n)) * (H_ * DV_) + h * DV_ + dv) = o;
}

// ---------------------------------------------------------------------------
extern "C" void kernel_launch(void* const* d_in, const int* in_sizes, int n_in,
                              void* d_out, int out_size, void* d_ws, size_t ws_size,
                              hipStream_t stream) {
    const float* x   = (const float*)d_in[0];
    const float* Wq  = (const float*)d_in[1];
    const float* bq  = (const float*)d_in[2];
    const float* Wk  = (const float*)d_in[3];
    const float* bk  = (const float*)d_in[4];
    const float* Wv  = (const float*)d_in[5];
    const float* bv  = (const float*)d_in[6];
    const float* WqL = (const float*)d_in[7];
    const float* bqL = (const float*)d_in[8];
    const float* WkL = (const float*)d_in[9];
    const float* bkL = (const float*)d_in[10];
    const float* WvL = (const float*)d_in[11];
    const float* bvL = (const float*)d_in[12];
    const float* Wo  = (const float*)d_in[13];
    const float* bo  = (const float*)d_in[14];

    ushort* Wt_all = (ushort*)d_ws;                          // [2048][512] bf16
    ushort* Wot    = Wt_all + (size_t)3 * DM_ * DM_;
    float*  fb     = (float*)(Wt_all + (size_t)4 * DM_ * DM_); // [1536] f32
    ushort* xbf    = (ushort*)(fb + 3 * DM_);                // [4096][512]
    ushort* Qd     = xbf + (size_t)BN_ * DM_;
    ushort* Kd     = Qd + (size_t)B_ * H_ * N_ * DK_;
    ushort* Vtd    = Kd + (size_t)B_ * H_ * N_ * DK_;        // [B,H,DV,N]
    ushort* Od     = Vtd + (size_t)B_ * H_ * N_ * DV_;       // [B,N,H*DV]
    ushort* Opart  = Od + (size_t)B_ * H_ * N_ * DV_;        // [4][B*H,N,DV]
    float2* Ml     = (float2*)(Opart + (size_t)SPLITS * B_ * H_ * N_ * DV_);

    float* out = (float*)d_out;

    prep<<<1542, 256, 0, stream>>>(Wq, WqL, Wk, WkL, Wv, WvL, Wo, Wt_all,
                                   x, xbf, bq, bqL, bk, bkL, bv, bvL, fb);

    gemm_bf16<64, 0><<<dim3(32, 24), 256, 0, stream>>>(xbf, Wt_all, fb, Qd, Kd, Vtd, nullptr);
    attn_mfma<<<dim3(16, 16, SPLITS), 512, 0, stream>>>(Qd, Kd, Vtd, Opart, Ml);
    merge_splits<<<(B_ * H_ * N_ * 16) / 256, 256, 0, stream>>>(Opart, Ml, Od);
    gemm_bf16<32, 1><<<dim3(32, 16), 256, 0, stream>>>(Od, Wot, bo, nullptr, nullptr, nullptr, out);
}